// Round 8
// baseline (1072.773 us; speedup 1.0000x reference)
//
#include <hip/hip_runtime.h>

// ---------------------------------------------------------------------------
// GIN 2-layer forward (bf16 features, MFMA GEMMs, CSR gather segment-sum):
//   CSR bucket edges by dst (hist -> parallel scan -> fill, packed src|dst<<16)
//   p1 = bf16( x @ w1a )                      [b1a cancels in BN]
//   s1 = bf16( p1[n] + segsum )               (edge-parallel, LDS fp32 acc)
//   h1 = bf16( relu( relu(sc1*s1+sh1) @ w1b + b1b ) )
//   p2 = bf16( h1 @ w2a )                     [b2a cancels in BN]
//   s2 = bf16( p2[n] + segsum )
//   out = log_softmax( relu(sc2*s2+sh2) @ w2b + b2b )  fp32, fused epilogue
// segsum_ep: block = 32 dst nodes = contiguous edge range; edge list staged in
// LDS once (coalesced); 4 edges in flight per wave step (independent ushort
// gathers); ds_add_f32 accumulate (2-way bank alias = free).
// ---------------------------------------------------------------------------

typedef unsigned short u16;
typedef unsigned int u32;
typedef __attribute__((ext_vector_type(8))) short short8;
typedef __attribute__((ext_vector_type(4))) short short4v;
typedef __attribute__((ext_vector_type(4))) float f32x4;

#define DEV_INLINE __device__ __forceinline__

DEV_INLINE void atomAddF(float* p, float v) { unsafeAtomicAdd(p, v); }

DEV_INLINE u16 f2bf(float f) {
    unsigned u = __float_as_uint(f);
    u += 0x7fffu + ((u >> 16) & 1u);   // round-to-nearest-even
    return (u16)(u >> 16);
}
DEV_INLINE float bf2f(u16 h) { return __uint_as_float(((unsigned)h) << 16); }

// ---------------------------------------------------------------------------
// Weight prep (all 4 weights, one launch): W[K][NOUT] fp32 -> frag-ordered
// bf16 (MFMA A-operand, swapped). unit=(ct,kc,lane): 8 bf16 for
// col=ct*16+(lane&15), k=kc*32+(lane>>4)*8+j.
// ---------------------------------------------------------------------------
__global__ __launch_bounds__(256) void wprep4_k(
    const float* __restrict__ w1a, const float* __restrict__ w1b,
    const float* __restrict__ w2a, const float* __restrict__ w2b,
    short* __restrict__ o1a, short* __restrict__ o1b,
    short* __restrict__ o2a, short* __restrict__ o2b)
{
    int b = blockIdx.x;
    const float* W; short* wf; int K, NOUT;
    if (b < 8)       { W = w1a; wf = o1a; K = 128; NOUT = 128; }
    else if (b < 16) { W = w1b; wf = o1b; K = 128; NOUT = 128; b -= 8; }
    else if (b < 20) { W = w2a; wf = o2a; K = 128; NOUT = 64;  b -= 16; }
    else             { W = w2b; wf = o2b; K = 64;  NOUT = 64;  b -= 20; }
    const int u = b * 256 + threadIdx.x;
    const int units = (NOUT / 16) * (K / 32) * 64;
    if (u >= units) return;
    const int per_ct = (K / 32) * 64;
    const int ct = u / per_ct;
    const int rem = u % per_ct;
    const int kc = rem >> 6;
    const int l = rem & 63;
    const int col = ct * 16 + (l & 15);
    const int k0 = kc * 32 + (l >> 4) * 8;
    short8 pk;
#pragma unroll
    for (int j = 0; j < 8; j++)
        pk[j] = (short)f2bf(W[(size_t)(k0 + j) * NOUT + col]);
    *(short8*)&wf[(size_t)u * 8] = pk;
}

// ---------------------------------------------------------------------------
// MFMA GEMM (swapped operands => per-lane contiguous C-writes):
//   out[M][NC] = f(A[M][KD]) @ W  (+bias) (+relu | +row log_softmax)
// A is fp32 or bf16; out is bf16 or fp32. BM=128 rows, 256 threads (4 waves).
// ---------------------------------------------------------------------------
template <int KD, int NC, bool ABF16, bool BNIN, bool BIAS, bool RELUOUT,
          bool LOGSM, bool OBF16>
__global__ __launch_bounds__(256) void mgemm(
    const void* __restrict__ Ap, const short* __restrict__ Wf,
    const float* __restrict__ sc, const float* __restrict__ sh,
    const float* __restrict__ bias, void* __restrict__ outp, int M)
{
    constexpr int BM = 128;
    constexpr int KC = KD / 32;   // 32-wide k chunks
    constexpr int CT = NC / 16;   // 16-wide col tiles
    __shared__ short Asl[BM * KD];
    __shared__ short Bsl[NC * KD];

    const int t = threadIdx.x;
    const int l = t & 63;
    const int w = t >> 6;

    // ---- stage B: frag-ordered weights, linear copy ----
    {
        const float4* src = (const float4*)Wf;
        float4* dst = (float4*)Bsl;
        constexpr int NU = NC * KD / 8;
#pragma unroll
        for (int u = t; u < NU; u += 256) dst[u] = src[u];
    }
    // ---- stage A: 2 threads per row -> (BN+ReLU) -> bf16 frags ----
    {
        const int r = t >> 1;
        const int half = t & 1;
        const int grow = blockIdx.x * BM + r;
        const int rt = r >> 4;
        constexpr int KH = KD / 2;
        u16 hv[KH];
        if (grow < M) {
            if constexpr (ABF16) {
                const u16* ap = (const u16*)Ap + (size_t)grow * KD + half * KH;
#pragma unroll
                for (int i = 0; i < KH / 8; i++)
                    *(short8*)&hv[i * 8] = ((const short8*)ap)[i];
                if constexpr (BNIN) {
#pragma unroll
                    for (int i = 0; i < KH; i++) {
                        const int k = half * KH + i;
                        hv[i] = f2bf(fmaxf(0.f, bf2f(hv[i]) * sc[k] + sh[k]));
                    }
                }
            } else {
                const float* ap = (const float*)Ap + (size_t)grow * KD + half * KH;
#pragma unroll
                for (int i = 0; i < KH / 4; i++) {
                    const float4 v = ((const float4*)ap)[i];
                    float f0 = v.x, f1 = v.y, f2 = v.z, f3 = v.w;
                    if constexpr (BNIN) {
                        const int k = half * KH + i * 4;
                        f0 = fmaxf(0.f, f0 * sc[k + 0] + sh[k + 0]);
                        f1 = fmaxf(0.f, f1 * sc[k + 1] + sh[k + 1]);
                        f2 = fmaxf(0.f, f2 * sc[k + 2] + sh[k + 2]);
                        f3 = fmaxf(0.f, f3 * sc[k + 3] + sh[k + 3]);
                    }
                    hv[i * 4 + 0] = f2bf(f0); hv[i * 4 + 1] = f2bf(f1);
                    hv[i * 4 + 2] = f2bf(f2); hv[i * 4 + 3] = f2bf(f3);
                }
            }
        } else {
#pragma unroll
            for (int i = 0; i < KH; i++) hv[i] = 0;
        }
#pragma unroll
        for (int g = 0; g < KH / 8; g++) {
            const int k0 = half * KH + g * 8;
            const int kc = k0 >> 5;
            const int lane = (r & 15) + ((k0 >> 3) & 3) * 16;
            *(short8*)&Asl[((rt * KC + kc) * 64 + lane) * 8] =
                *(short8*)&hv[g * 8];
        }
    }
    __syncthreads();

    // ---- MFMA: wave w owns row-tiles {2w, 2w+1} x all col-tiles ----
    const int rt0 = w * 2;
    f32x4 acc[2][CT];
#pragma unroll
    for (int i = 0; i < 2; i++)
#pragma unroll
        for (int c = 0; c < CT; c++) acc[i][c] = (f32x4){0.f, 0.f, 0.f, 0.f};

#pragma unroll
    for (int kc = 0; kc < KC; kc++) {
        const short8 x0 = *(const short8*)&Asl[((rt0 * KC + kc) * 64 + l) * 8];
        const short8 x1 = *(const short8*)&Asl[(((rt0 + 1) * KC + kc) * 64 + l) * 8];
#pragma unroll
        for (int ct = 0; ct < CT; ct++) {
            const short8 wb = *(const short8*)&Bsl[((ct * KC + kc) * 64 + l) * 8];
            acc[0][ct] = __builtin_amdgcn_mfma_f32_16x16x32_bf16(wb, x0, acc[0][ct], 0, 0, 0);
            acc[1][ct] = __builtin_amdgcn_mfma_f32_16x16x32_bf16(wb, x1, acc[1][ct], 0, 0, 0);
        }
    }

    // ---- epilogue: lane l holds row (l&15), cols (l>>4)*4+{0..3} of tile ----
    const int cbase = (l >> 4) * 4;
#pragma unroll
    for (int rr = 0; rr < 2; rr++) {
        const int grow = blockIdx.x * BM + (rt0 + rr) * 16 + (l & 15);
        if constexpr (!LOGSM) {
            if (grow < M) {
#pragma unroll
                for (int ct = 0; ct < CT; ct++) {
                    f32x4 o = acc[rr][ct];
                    if constexpr (BIAS) {
                        const float4 bv = *(const float4*)&bias[ct * 16 + cbase];
                        o[0] += bv.x; o[1] += bv.y; o[2] += bv.z; o[3] += bv.w;
                    }
                    if constexpr (RELUOUT) {
#pragma unroll
                        for (int j = 0; j < 4; j++) o[j] = fmaxf(o[j], 0.f);
                    }
                    if constexpr (OBF16) {
                        short4v o16;
#pragma unroll
                        for (int j = 0; j < 4; j++) o16[j] = (short)f2bf(o[j]);
                        *(short4v*)&((u16*)outp)[(size_t)grow * NC + ct * 16 + cbase] = o16;
                    } else {
                        *(f32x4*)&((float*)outp)[(size_t)grow * NC + ct * 16 + cbase] = o;
                    }
                }
            }
        } else {
            // fused row log_softmax (row spread across lanes l, l^16, l^32, l^48)
            float v[CT * 4];
#pragma unroll
            for (int ct = 0; ct < CT; ct++) {
                const float4 bv = *(const float4*)&bias[ct * 16 + cbase];
                v[ct * 4 + 0] = acc[rr][ct][0] + bv.x;
                v[ct * 4 + 1] = acc[rr][ct][1] + bv.y;
                v[ct * 4 + 2] = acc[rr][ct][2] + bv.z;
                v[ct * 4 + 3] = acc[rr][ct][3] + bv.w;
            }
            float m = v[0];
#pragma unroll
            for (int j = 1; j < CT * 4; j++) m = fmaxf(m, v[j]);
            m = fmaxf(m, __shfl_xor(m, 16));
            m = fmaxf(m, __shfl_xor(m, 32));
            float s = 0.f;
#pragma unroll
            for (int j = 0; j < CT * 4; j++) s += __expf(v[j] - m);
            s += __shfl_xor(s, 16);
            s += __shfl_xor(s, 32);
            const float lg = m + __logf(s);
            if (grow < M) {
#pragma unroll
                for (int ct = 0; ct < CT; ct++) {
                    f32x4 o;
#pragma unroll
                    for (int j = 0; j < 4; j++) o[j] = v[ct * 4 + j] - lg;
                    *(f32x4*)&((float*)outp)[(size_t)grow * NC + ct * 16 + cbase] = o;
                }
            }
        }
    }
}

// ---------------------------------------------------------------------------
// CSR build: histogram, 3-kernel parallel exclusive scan, bucket fill.
// fill packs (src | dst<<16): both < 65536 for this problem (N = 50000).
// ---------------------------------------------------------------------------
__global__ __launch_bounds__(256) void hist_k(const int* __restrict__ ei,
                                              int* __restrict__ cnt, int E)
{
    const int gid = blockIdx.x * blockDim.x + threadIdx.x;
    const int stride = gridDim.x * blockDim.x;
    for (int e = gid; e < E; e += stride) atomicAdd(&cnt[ei[E + e]], 1);
}

__global__ __launch_bounds__(256) void bsum_k(const int* __restrict__ cnt,
                                              int* __restrict__ bsum, int N)
{
    __shared__ int ws[4];
    const int i = blockIdx.x * 256 + threadIdx.x;
    int v = (i < N) ? cnt[i] : 0;
    for (int d = 32; d; d >>= 1) v += __shfl_xor(v, d, 64);
    if ((threadIdx.x & 63) == 0) ws[threadIdx.x >> 6] = v;
    __syncthreads();
    if (threadIdx.x == 0) bsum[blockIdx.x] = ws[0] + ws[1] + ws[2] + ws[3];
}

// single block; G1 <= 256
__global__ __launch_bounds__(256) void bscan_k(const int* __restrict__ bsum,
                                               int* __restrict__ bpre, int G1)
{
    __shared__ int part[256];
    const int t = threadIdx.x;
    const int v = (t < G1) ? bsum[t] : 0;
    part[t] = v;
    __syncthreads();
    for (int d = 1; d < 256; d <<= 1) {
        const int u = (t >= d) ? part[t - d] : 0;
        __syncthreads();
        part[t] += u;
        __syncthreads();
    }
    bpre[t] = part[t] - v;   // exclusive
}

__global__ __launch_bounds__(256) void offs_k(const int* __restrict__ cnt,
                                              const int* __restrict__ bpre,
                                              int* __restrict__ off,
                                              int* __restrict__ cursor,
                                              int N, int E)
{
    __shared__ int part[256];
    const int t = threadIdx.x;
    const int i = blockIdx.x * 256 + t;
    const int v = (i < N) ? cnt[i] : 0;
    part[t] = v;
    __syncthreads();
    for (int d = 1; d < 256; d <<= 1) {
        const int u = (t >= d) ? part[t - d] : 0;
        __syncthreads();
        part[t] += u;
        __syncthreads();
    }
    if (i < N) {
        const int o = bpre[blockIdx.x] + part[t] - v;
        off[i] = o;
        cursor[i] = o;
    }
    if (blockIdx.x == 0 && t == 0) off[N] = E;
}

__global__ __launch_bounds__(256) void fill_k(const int* __restrict__ ei,
                                              int* __restrict__ cursor,
                                              u32* __restrict__ epack, int E)
{
    const int gid = blockIdx.x * blockDim.x + threadIdx.x;
    const int stride = gridDim.x * blockDim.x;
    for (int e = gid; e < E; e += stride) {
        const int s = ei[e];
        const int d = ei[E + e];
        const int pos = atomicAdd(&cursor[d], 1);
        epack[pos] = (u32)s | ((u32)d << 16);
    }
}

// ---------------------------------------------------------------------------
// Edge-parallel segment-sum (bf16 in/out) + fused column stats.
// Block = 32 consecutive dst nodes = contiguous CSR edge range.
// Edge list staged in LDS (one coalesced pass); waves take 4-edge groups:
// 4 (C=64) or 8 (C=128) independent ushort gathers in flight, then
// ds_add_f32 into acc[node][ch] (lane -> ch l and l+64: 2-way alias, free).
// ---------------------------------------------------------------------------
template <int C>
__global__ __launch_bounds__(256) void segsum_ep(
    const u16* __restrict__ p, const int* __restrict__ off,
    const u32* __restrict__ epack, u16* __restrict__ out,
    float* __restrict__ sum, float* __restrict__ sumsq, int N)
{
    constexpr int NB = 32;             // nodes per block
    constexpr int VPL = C / 64;        // channels per lane (2 or 1)
    constexpr int EBUF = 1024;
    __shared__ float acc[NB][C];       // 16 KB (C=128) / 8 KB (C=64)
    __shared__ u32 ebuf[EBUF];         // 4 KB

    const int tid = threadIdx.x;
    const int wv = tid >> 6;
    const int l = tid & 63;
    const int n0 = blockIdx.x * NB;
    const int nend = min(n0 + NB, N);
    const int elo = off[n0];
    const int ehi = off[nend];

    // zero accumulators
    for (int i = tid; i < NB * C; i += 256) (&acc[0][0])[i] = 0.f;

    for (int ebase = elo; ebase < ehi; ebase += EBUF) {
        const int ecnt = min(EBUF, ehi - ebase);
        __syncthreads();   // protect ebuf (prev chunk) and first-pass acc zero
        for (int k = tid; k < ecnt; k += 256) ebuf[k] = epack[ebase + k];
        __syncthreads();

        const int ngrp = (ecnt + 3) / 4;
        for (int g = wv; g < ngrp; g += 4) {
            const int e0 = g * 4;
            const int m = min(4, ecnt - e0);   // wave-uniform
            u32 pk[4];
#pragma unroll
            for (int j = 0; j < 4; j++) pk[j] = ebuf[e0 + (j < m ? j : 0)];
            u16 ga[4], gb[4];
#pragma unroll
            for (int j = 0; j < 4; j++) {
                const int s = (int)(pk[j] & 0xFFFFu);
                ga[j] = p[(size_t)s * C + l];
                if constexpr (VPL == 2) gb[j] = p[(size_t)s * C + 64 + l];
            }
#pragma unroll
            for (int j = 0; j < 4; j++) {
                if (j < m) {
                    const int d = (int)(pk[j] >> 16) - n0;
                    atomicAdd(&acc[d][l], bf2f(ga[j]));
                    if constexpr (VPL == 2)
                        atomicAdd(&acc[d][64 + l], bf2f(gb[j]));
                }
            }
        }
    }
    __syncthreads();

    // epilogue: add self row, round, write, per-thread stats
    float ss[VPL], qq[VPL];
#pragma unroll
    for (int v = 0; v < VPL; v++) { ss[v] = 0.f; qq[v] = 0.f; }

    for (int i = 0; i < NB / 4; i++) {
        const int n = i * 4 + wv;
        const int gn = n0 + n;
        if (gn < N) {
#pragma unroll
            for (int v = 0; v < VPL; v++) {
                const int ch = v * 64 + l;
                const float val = acc[n][ch] + bf2f(p[(size_t)gn * C + ch]);
                const u16 r = f2bf(val);
                out[(size_t)gn * C + ch] = r;
                const float f = bf2f(r);
                ss[v] += f;
                qq[v] += f * f;
            }
        }
    }

    // cross-wave reduce in LDS (reuse ebuf), one atomic per channel per block
    float* red = (float*)ebuf;   // needs 256 * 2 * VPL floats <= 1024
    __syncthreads();
#pragma unroll
    for (int v = 0; v < VPL; v++) {
        red[v * 512 + tid] = ss[v];
        red[v * 512 + 256 + tid] = qq[v];
    }
    __syncthreads();
    if (wv == 0) {
#pragma unroll
        for (int v = 0; v < VPL; v++) {
            float a = 0.f, b = 0.f;
#pragma unroll
            for (int w2 = 0; w2 < 4; w2++) {
                a += red[v * 512 + w2 * 64 + l];
                b += red[v * 512 + 256 + w2 * 64 + l];
            }
            atomAddF(&sum[v * 64 + l], a);
            atomAddF(&sumsq[v * 64 + l], b);
        }
    }
}

__global__ void bnfinal_k(const float* __restrict__ sum,
                          const float* __restrict__ sumsq,
                          const float* __restrict__ g,
                          const float* __restrict__ be,
                          float* __restrict__ sc, float* __restrict__ sh,
                          int C, float invN)
{
    const int c = threadIdx.x;
    if (c < C) {
        const float m = sum[c] * invN;
        const float v = sumsq[c] * invN - m * m;
        const float r = rsqrtf(v + 1e-5f);
        const float s = g[c] * r;
        sc[c] = s;
        sh[c] = be[c] - m * s;
    }
}

extern "C" void kernel_launch(void* const* d_in, const int* in_sizes, int n_in,
                              void* d_out, int out_size, void* d_ws, size_t ws_size,
                              hipStream_t stream)
{
    const float* x   = (const float*)d_in[0];
    const int*   ei  = (const int*)d_in[1];
    const float* w1a = (const float*)d_in[2];
    // d_in[3] = b1a: cancelled by BN
    const float* g1  = (const float*)d_in[4];
    const float* be1 = (const float*)d_in[5];
    const float* w1b = (const float*)d_in[6];
    const float* b1b = (const float*)d_in[7];
    const float* w2a = (const float*)d_in[8];
    // d_in[9] = b2a: cancelled by BN
    const float* g2  = (const float*)d_in[10];
    const float* be2 = (const float*)d_in[11];
    const float* w2b = (const float*)d_in[12];
    const float* b2b = (const float*)d_in[13];
    float* out = (float*)d_out;

    const int N = in_sizes[0] / 128;   // 50000  (< 65536: packing valid)
    const int E = in_sizes[1] / 2;     // 800000

    // ---- workspace layout ----
    u16* buf1 = (u16*)d_ws;                      // N*128 bf16 : p1, then h1
    u16* buf2 = buf1 + (size_t)N * 128;          // N*128 bf16 : s1, then p2|s2
    float* stats = (float*)(buf2 + (size_t)N * 128);  // 1024 floats
    float* sum1 = stats,       *sq1 = stats + 128;
    float* sum2 = stats + 256, *sq2 = stats + 320;
    float* sc1  = stats + 384, *sh1 = stats + 512;
    float* sc2  = stats + 640, *sh2 = stats + 704;
    int* cnt    = (int*)(stats + 1024);          // N
    int* off    = cnt + N;                       // N+1
    int* cursor = off + N + 1;                   // N
    u32* epack  = (u32*)(cursor + N);            // E (packed src|dst<<16)
    int* bsum   = (int*)(epack + E);             // 256
    int* bpre   = bsum + 256;                    // 256
    short* w1af = (short*)(bpre + 256);          // 128*128
    short* w1bf = w1af + 128 * 128;              // 128*128
    short* w2af = w1bf + 128 * 128;              // 128*64
    short* w2bf = w2af + 128 * 64;               // 64*64
    u16* p1 = buf1;
    u16* s1 = buf2;
    u16* h1 = buf1;                    // reuse: p1 dead after segsum1
    u16* p2 = buf2;                    // reuse: s1 dead after mgemm2 (N*64)
    u16* s2 = buf2 + (size_t)N * 64;   // upper half

    hipMemsetAsync(stats, 0, 1024 * sizeof(float) + (size_t)N * sizeof(int), stream);

    const int G1 = (N + 255) / 256;
    const int gb = (N + 127) / 128;
    const int gs = (N + 31) / 32;      // segsum_ep: 32 nodes per block

    // ---- CSR build ----
    hist_k<<<1024, 256, 0, stream>>>(ei, cnt, E);
    bsum_k<<<G1, 256, 0, stream>>>(cnt, bsum, N);
    bscan_k<<<1, 256, 0, stream>>>(bsum, bpre, G1);
    offs_k<<<G1, 256, 0, stream>>>(cnt, bpre, off, cursor, N, E);
    fill_k<<<1024, 256, 0, stream>>>(ei, cursor, epack, E);

    // ---- weight prep (one launch for all four) ----
    wprep4_k<<<22, 256, 0, stream>>>(w1a, w1b, w2a, w2b, w1af, w1bf, w2af, w2bf);

    // ---- Layer 1 ----
    mgemm<128, 128, false, false, false, false, false, true>
        <<<gb, 256, 0, stream>>>(x, w1af, nullptr, nullptr, nullptr, p1, N);
    segsum_ep<128><<<gs, 256, 0, stream>>>(p1, off, epack, s1, sum1, sq1, N);
    bnfinal_k<<<1, 128, 0, stream>>>(sum1, sq1, g1, be1, sc1, sh1, 128, 1.f / N);
    mgemm<128, 128, true, true, true, true, false, true>
        <<<gb, 256, 0, stream>>>(s1, w1bf, sc1, sh1, b1b, h1, N);

    // ---- Layer 2 (aggregate after projecting to 64ch) ----
    mgemm<128, 64, true, false, false, false, false, true>
        <<<gb, 256, 0, stream>>>(h1, w2af, nullptr, nullptr, nullptr, p2, N);
    segsum_ep<64><<<gs, 256, 0, stream>>>(p2, off, epack, s2, sum2, sq2, N);
    bnfinal_k<<<1, 64, 0, stream>>>(sum2, sq2, g2, be2, sc2, sh2, 64, 1.f / N);
    mgemm<64, 64, true, true, true, false, true, false>
        <<<gb, 256, 0, stream>>>(s2, w2bf, sc2, sh2, b2b, out, N);
}